// Round 1
// 972.557 us; speedup vs baseline: 1.0928x; 1.0928x over previous
//
#include <hip/hip_runtime.h>
#include <hip/hip_bf16.h>

typedef __bf16 bf16;
typedef bf16 v8bf __attribute__((ext_vector_type(8)));
typedef bf16 v4bf __attribute__((ext_vector_type(4)));
typedef float v4f __attribute__((ext_vector_type(4)));

constexpr int Bc = 2, Sc = 2048, Dc = 1024, Hc = 16, HDc = 64;
constexpr int Mr = Bc * Sc;  // 4096 rows for projection GEMMs

__device__ inline v4f mfma16(v8bf a, v8bf b, v4f c) {
    return __builtin_amdgcn_mfma_f32_16x16x32_bf16(a, b, c, 0, 0, 0);
}

__device__ inline void gload_lds16(const void* g, void* l) {
    __builtin_amdgcn_global_load_lds((__attribute__((address_space(1))) void*)g,
                                     (__attribute__((address_space(3))) void*)l, 16, 0, 0);
}

// ---------- weight transpose+cvt: fp32 W[k][n] -> bf16 Wt[n][k], 4 matrices stacked ----------
__global__ void wtrans_kernel(const float* __restrict__ Wq, const float* __restrict__ Wk,
                              const float* __restrict__ Wv, const float* __restrict__ Wo,
                              bf16* __restrict__ out) {
    __shared__ float t[32][33];
    const float* W = (blockIdx.z == 0) ? Wq : (blockIdx.z == 1) ? Wk : (blockIdx.z == 2) ? Wv : Wo;
    bf16* Wt = out + (size_t)blockIdx.z * (Dc * Dc);
    int x0 = blockIdx.x * 32, y0 = blockIdx.y * 32;
    int tx = threadIdx.x, ty = threadIdx.y;
#pragma unroll
    for (int i = 0; i < 4; i++)
        t[ty + 8 * i][tx] = W[(size_t)(y0 + ty + 8 * i) * Dc + x0 + tx];
    __syncthreads();
#pragma unroll
    for (int i = 0; i < 4; i++)
        Wt[(size_t)(x0 + ty + 8 * i) * Dc + y0 + tx] = (bf16)t[tx][ty + 8 * i];
}

// ---------- fp32 -> bf16 convert (vectorized) ----------
__global__ void cvt_kernel(const float* __restrict__ in, bf16* __restrict__ out) {
    size_t i = ((size_t)blockIdx.x * blockDim.x + threadIdx.x) * 8;
    float4 f0 = *(const float4*)(in + i);
    float4 f1 = *(const float4*)(in + i + 4);
    v8bf v;
    v[0] = (bf16)f0.x; v[1] = (bf16)f0.y; v[2] = (bf16)f0.z; v[3] = (bf16)f0.w;
    v[4] = (bf16)f1.x; v[5] = (bf16)f1.y; v[6] = (bf16)f1.z; v[7] = (bf16)f1.w;
    *(v8bf*)(out + i) = v;
}

// ---------- V transpose (bf16): per b, [S][D] -> [D][S] ----------
__global__ void vtrans_kernel(const bf16* __restrict__ V, bf16* __restrict__ Vt) {
    __shared__ bf16 t[32][33];
    int b = blockIdx.z;
    const bf16* Vb = V + (size_t)b * Sc * Dc;
    bf16* Vtb = Vt + (size_t)b * Dc * Sc;
    int s0 = blockIdx.x * 32, d0 = blockIdx.y * 32;
    int tx = threadIdx.x, ty = threadIdx.y;
#pragma unroll
    for (int i = 0; i < 4; i++)
        t[ty + 8 * i][tx] = Vb[(size_t)(s0 + ty + 8 * i) * Dc + d0 + tx];
    __syncthreads();
#pragma unroll
    for (int i = 0; i < 4; i++)
        Vtb[(size_t)(d0 + ty + 8 * i) * Sc + s0 + tx] = t[tx][ty + 8 * i];
}

// ---------- GEMM: Y[M][1024] = X[M][1024] @ W + bias, X bf16, Wt[n][k] bf16 ----------
// BM=128 BN=64 BK=64, 256 threads (4 waves 2x2 over 128x64), global_load_lds staging.
template <typename TOut>
__global__ __launch_bounds__(256) void gemm_kernel(const bf16* __restrict__ X,
                                                   const bf16* __restrict__ Wt,
                                                   const float* __restrict__ bias,
                                                   TOut* __restrict__ Y) {
    __shared__ bf16 As[128][64];  // linear, staged by global_load_lds
    __shared__ bf16 Bs[64][64];
    const int mTile = blockIdx.x * 128, nTile = blockIdx.y * 64;
    const int tid = threadIdx.x;
    const int w = tid >> 6, l = tid & 63, lr = l & 15, quad = l >> 4;
    const int wm = w & 1, wn = w >> 1;
    const int srow = l >> 3, scol = (l & 7) * 8;  // staging: 8 rows x 64 cols per instr

    v4f acc[4][2];
#pragma unroll
    for (int mt = 0; mt < 4; mt++)
#pragma unroll
        for (int nt = 0; nt < 2; nt++) acc[mt][nt] = v4f{0.f, 0.f, 0.f, 0.f};

    float bv[2];
#pragma unroll
    for (int nt = 0; nt < 2; nt++) bv[nt] = bias[nTile + wn * 32 + nt * 16 + lr];

    const bf16* Xbase = X + (size_t)mTile * Dc;
    const bf16* Wbase = Wt + (size_t)nTile * Dc;

    for (int kt = 0; kt < Dc; kt += 64) {
        __syncthreads();
#pragma unroll
        for (int i = 0; i < 4; i++) {
            int r = w * 32 + i * 8 + srow;
            gload_lds16(Xbase + (size_t)r * Dc + kt + scol, &As[w * 32 + i * 8][0]);
        }
#pragma unroll
        for (int i = 0; i < 2; i++) {
            int r = w * 16 + i * 8 + srow;
            gload_lds16(Wbase + (size_t)r * Dc + kt + scol, &Bs[w * 16 + i * 8][0]);
        }
        __syncthreads();

        v8bf a[4][2], bb[2][2];
#pragma unroll
        for (int mt = 0; mt < 4; mt++)
#pragma unroll
            for (int kk = 0; kk < 2; kk++)
                a[mt][kk] = *(const v8bf*)&As[wm * 64 + mt * 16 + lr][kk * 32 + quad * 8];
#pragma unroll
        for (int nt = 0; nt < 2; nt++)
#pragma unroll
            for (int kk = 0; kk < 2; kk++)
                bb[nt][kk] = *(const v8bf*)&Bs[wn * 32 + nt * 16 + lr][kk * 32 + quad * 8];
#pragma unroll
        for (int kk = 0; kk < 2; kk++)
#pragma unroll
            for (int mt = 0; mt < 4; mt++)
#pragma unroll
                for (int nt = 0; nt < 2; nt++)
                    acc[mt][nt] = mfma16(a[mt][kk], bb[nt][kk], acc[mt][nt]);
    }

#pragma unroll
    for (int mt = 0; mt < 4; mt++)
#pragma unroll
        for (int nt = 0; nt < 2; nt++)
#pragma unroll
            for (int r = 0; r < 4; r++) {
                int row = mTile + wm * 64 + mt * 16 + quad * 4 + r;
                int col = nTile + wn * 32 + nt * 16 + lr;
                Y[(size_t)row * Dc + col] = (TOut)(acc[mt][nt][r] + bv[nt]);
            }
}

// ---------- fused attention: swapped QK^T (S^T layout), no block barriers in loops ----------
// grid (S/64, H, B), 256 threads = 4 waves; wave w owns 16 query rows (q = r0 + lr).
__global__ __launch_bounds__(256) void attn_kernel(const bf16* __restrict__ Q,
                                                   const bf16* __restrict__ K,
                                                   const bf16* __restrict__ Vt,
                                                   float* __restrict__ attn,
                                                   bf16* __restrict__ ctx) {
    __shared__ bf16 Ps[4][16][40];  // per-wave P tile [q=16][k=32], 80B row stride
    const int b = blockIdx.z, h = blockIdx.y, rb = blockIdx.x;
    const int tid = threadIdx.x, w = tid >> 6, l = tid & 63, lr = l & 15, quad = l >> 4;
    const int r0 = rb * 64 + w * 16;
    const float scale = 0.125f;  // 1/sqrt(64)

    const bf16* Qrow = Q + (size_t)(b * Sc + r0 + lr) * Dc + h * HDc;
    v8bf qa0 = *(const v8bf*)(Qrow + quad * 8);
    v8bf qa1 = *(const v8bf*)(Qrow + 32 + quad * 8);

    const bf16* Kbase = K + (size_t)(b * Sc) * Dc + h * HDc;

    // pass 1: row sums of exp(s). Swapped mfma(K,Q): lane owns q=lr, k=quad*4+r.
    float sum = 0.f, sumB = 0.f;
    for (int ct = 0; ct < Sc / 16; ct += 2) {
        const bf16* Kr0 = Kbase + (size_t)(ct * 16 + lr) * Dc;
        const bf16* Kr1 = Kr0 + 16 * Dc;
        v8bf k00 = *(const v8bf*)(Kr0 + quad * 8);
        v8bf k01 = *(const v8bf*)(Kr0 + 32 + quad * 8);
        v8bf k10 = *(const v8bf*)(Kr1 + quad * 8);
        v8bf k11 = *(const v8bf*)(Kr1 + 32 + quad * 8);
        v4f s0 = v4f{0.f, 0.f, 0.f, 0.f}, s1 = v4f{0.f, 0.f, 0.f, 0.f};
        s0 = mfma16(k00, qa0, s0);
        s0 = mfma16(k01, qa1, s0);
        s1 = mfma16(k10, qa0, s1);
        s1 = mfma16(k11, qa1, s1);
#pragma unroll
        for (int r = 0; r < 4; r++) sum += __expf(s0[r] * scale);
#pragma unroll
        for (int r = 0; r < 4; r++) sumB += __expf(s1[r] * scale);
    }
    sum += sumB;
    sum += __shfl_xor(sum, 16);  // reduce across quads (k-partition)
    sum += __shfl_xor(sum, 32);
    const float inv = 1.0f / sum;

    float* attnRow = attn + ((size_t)((b * Hc + h) * Sc + r0 + lr)) * Sc;
    const bf16* VtBase = Vt + (size_t)(b * Dc + h * HDc) * Sc;

    v4f acc[4];
#pragma unroll
    for (int nt = 0; nt < 4; nt++) acc[nt] = v4f{0.f, 0.f, 0.f, 0.f};

    constexpr int NT = Sc / 32;  // 64 iterations over 32-key groups
    // prologue: load K/V fragments for ctp = 0
    v8bf k00, k01, k10, k11, vb[4];
    {
        const bf16* Kr0 = Kbase + (size_t)lr * Dc;
        const bf16* Kr1 = Kr0 + 16 * Dc;
        k00 = *(const v8bf*)(Kr0 + quad * 8);
        k01 = *(const v8bf*)(Kr0 + 32 + quad * 8);
        k10 = *(const v8bf*)(Kr1 + quad * 8);
        k11 = *(const v8bf*)(Kr1 + 32 + quad * 8);
#pragma unroll
        for (int nt = 0; nt < 4; nt++)
            vb[nt] = *(const v8bf*)(VtBase + (size_t)(nt * 16 + lr) * Sc + quad * 8);
    }

    for (int ctp = 0; ctp < NT; ctp++) {
        v4f s0 = v4f{0.f, 0.f, 0.f, 0.f}, s1 = v4f{0.f, 0.f, 0.f, 0.f};
        s0 = mfma16(k00, qa0, s0);
        s0 = mfma16(k01, qa1, s0);
        s1 = mfma16(k10, qa0, s1);
        s1 = mfma16(k11, qa1, s1);

        // prefetch next iteration's K and Vt fragments (hidden under exp + PV)
        const int nc = (ctp + 1 < NT) ? ctp + 1 : ctp;
        const bf16* Kr0n = Kbase + (size_t)(nc * 32 + lr) * Dc;
        const bf16* Kr1n = Kr0n + 16 * Dc;
        v8bf n00 = *(const v8bf*)(Kr0n + quad * 8);
        v8bf n01 = *(const v8bf*)(Kr0n + 32 + quad * 8);
        v8bf n10 = *(const v8bf*)(Kr1n + quad * 8);
        v8bf n11 = *(const v8bf*)(Kr1n + 32 + quad * 8);
        v8bf vn[4];
#pragma unroll
        for (int nt = 0; nt < 4; nt++)
            vn[nt] = *(const v8bf*)(VtBase + (size_t)(nt * 16 + lr) * Sc + nc * 32 + quad * 8);

        // softmax values: lane owns q=lr, k = ctp*32 + quad*4 + r (+16 for tile1)
        v4f p0, p1;
        v4bf pb0, pb1;
#pragma unroll
        for (int r = 0; r < 4; r++) {
            p0[r] = __expf(s0[r] * scale) * inv;
            pb0[r] = (bf16)p0[r];
        }
#pragma unroll
        for (int r = 0; r < 4; r++) {
            p1[r] = __expf(s1[r] * scale) * inv;
            pb1[r] = (bf16)p1[r];
        }
        // float4 non-temporal stores: 4 consecutive columns per lane
        __builtin_nontemporal_store(p0, (v4f*)(attnRow + ctp * 32 + quad * 4));
        __builtin_nontemporal_store(p1, (v4f*)(attnRow + ctp * 32 + 16 + quad * 4));
        // stash bf16 P in per-wave LDS in A-operand row-major layout
        *(v4bf*)&Ps[w][lr][quad * 4] = pb0;
        *(v4bf*)&Ps[w][lr][16 + quad * 4] = pb1;
        asm volatile("s_waitcnt lgkmcnt(0)" ::: "memory");  // wave-local: DS in-order per wave
        __builtin_amdgcn_sched_barrier(0);
        v8bf pa = *(const v8bf*)&Ps[w][lr][quad * 8];
#pragma unroll
        for (int nt = 0; nt < 4; nt++) acc[nt] = mfma16(pa, vb[nt], acc[nt]);

        k00 = n00; k01 = n01; k10 = n10; k11 = n11;
#pragma unroll
        for (int nt = 0; nt < 4; nt++) vb[nt] = vn[nt];
    }

#pragma unroll
    for (int nt = 0; nt < 4; nt++)
#pragma unroll
        for (int r = 0; r < 4; r++) {
            size_t row = (size_t)(b * Sc + r0 + quad * 4 + r);
            ctx[row * Dc + h * HDc + nt * 16 + lr] = (bf16)acc[nt][r];
        }
}

extern "C" void kernel_launch(void* const* d_in, const int* in_sizes, int n_in,
                              void* d_out, int out_size, void* d_ws, size_t ws_size,
                              hipStream_t stream) {
    const float* q  = (const float*)d_in[0];
    const float* k  = (const float*)d_in[1];
    const float* v  = (const float*)d_in[2];
    // d_in[3] = attn_mask: mathematically unused by the reference
    const float* Wq = (const float*)d_in[4];
    const float* bq = (const float*)d_in[5];
    const float* Wk = (const float*)d_in[6];
    const float* bk = (const float*)d_in[7];
    const float* Wv = (const float*)d_in[8];
    const float* bv = (const float*)d_in[9];
    const float* Wo = (const float*)d_in[10];
    const float* bo = (const float*)d_in[11];

    char* ws = (char*)d_ws;
    const size_t MB8 = 8388608;
    bf16* T0  = (bf16*)(ws);             // 8 MB: bf16 of current input tensor
    bf16* Qbf = (bf16*)(ws + 1 * MB8);   // 8 MB
    bf16* Kbf = (bf16*)(ws + 2 * MB8);   // 8 MB
    bf16* Vbf = (bf16*)(ws + 3 * MB8);   // 8 MB
    bf16* Vt  = (bf16*)(ws + 4 * MB8);   // 8 MB
    bf16* Wts = (bf16*)(ws + 5 * MB8);   // 8 MB: 4 x 2 MB stacked [n][k]
    bf16* Wqt = Wts;
    bf16* Wkt = Wts + 1 * (size_t)(Dc * Dc);
    bf16* Wvt = Wts + 2 * (size_t)(Dc * Dc);
    bf16* Wot = Wts + 3 * (size_t)(Dc * Dc);
    bf16* ctx = Vbf;  // reuse: Vbf dead after vtrans

    float* outp = (float*)d_out;
    float* attn = outp + (size_t)Mr * Dc;  // offset 4,194,304

    wtrans_kernel<<<dim3(32, 32, 4), dim3(32, 8), 0, stream>>>(Wq, Wk, Wv, Wo, Wts);

    cvt_kernel<<<dim3(2048), 256, 0, stream>>>(q, T0);
    gemm_kernel<bf16><<<dim3(32, 16), 256, 0, stream>>>(T0, Wqt, bq, Qbf);
    cvt_kernel<<<dim3(2048), 256, 0, stream>>>(k, T0);
    gemm_kernel<bf16><<<dim3(32, 16), 256, 0, stream>>>(T0, Wkt, bk, Kbf);
    cvt_kernel<<<dim3(2048), 256, 0, stream>>>(v, T0);
    gemm_kernel<bf16><<<dim3(32, 16), 256, 0, stream>>>(T0, Wvt, bv, Vbf);

    vtrans_kernel<<<dim3(64, 32, 2), dim3(32, 8), 0, stream>>>(Vbf, Vt);
    attn_kernel<<<dim3(32, 16, 2), 256, 0, stream>>>(Qbf, Kbf, Vt, attn, ctx);
    gemm_kernel<float><<<dim3(32, 16), 256, 0, stream>>>(ctx, Wot, bo, outp);
}